// Round 4
// baseline (820.551 us; speedup 1.0000x reference)
//
#include <hip/hip_runtime.h>
#include <stdint.h>

typedef unsigned short ushort_t;
typedef __attribute__((ext_vector_type(8))) __bf16 bf16x8;
typedef __attribute__((ext_vector_type(4))) float f32x4;
typedef __attribute__((ext_vector_type(4))) uint32_t u32x4;
typedef __attribute__((ext_vector_type(4))) float float4_t;

#define GPTR(x) ((__attribute__((address_space(1))) void*)(x))
#define LPTR(x) ((__attribute__((address_space(3))) void*)(x))

__device__ __forceinline__ ushort_t f2b(float f) {
  union { float f; uint32_t i; } v; v.f = f;
  uint32_t x = v.i;
  uint32_t r = (x + 0x7FFFu + ((x >> 16) & 1u)) >> 16;  // RNE; finite data only
  return (ushort_t)r;
}

__device__ __forceinline__ void spline_expand(float x, float* sil, float* b /*8*/) {
  *sil = x / (1.0f + __expf(-x));
  float g[12];
#pragma unroll
  for (int j = 0; j < 12; ++j) g[j] = (float)(j - 3) * 0.4f - 1.0f;
  float t[11];
#pragma unroll
  for (int j = 0; j < 11; ++j) t[j] = (x >= g[j] && x < g[j + 1]) ? 1.0f : 0.0f;
#pragma unroll
  for (int k = 1; k <= 3; ++k) {
#pragma unroll
    for (int j = 0; j + k < 11; ++j) {
      float i1 = 1.0f / (g[j + k] - g[j]);        // constant-folded after unroll
      float i2 = 1.0f / (g[j + k + 1] - g[j + 1]);
      t[j] = (x - g[j]) * i1 * t[j] + (g[j + k + 1] - x) * i2 * t[j + 1];
    }
  }
#pragma unroll
  for (int k = 0; k < 8; ++k) b[k] = t[k];
}

#define FPC 1024  // features per chunk; LDS = FPC*9 ushorts = 18432 B

// x[row, in_f] fp32 -> A[row, LDE] bf16 augmented [silu,B0..7]*in_f + zero pad.
// grid: (rows, ceil(LDE/(FPC*9))). LDS-staged, coalesced 16B stores.
__global__ __launch_bounds__(256) void expand_stage(
    const float* __restrict__ xin, ushort_t* __restrict__ A, int in_f, int LDE) {
  __shared__ __align__(16) ushort_t sb[FPC * 9];
  const int row = blockIdx.x, chunk = blockIdx.y, tid = threadIdx.x;
  const int e0 = chunk * (FPC * 9);
  int e1 = e0 + FPC * 9; if (e1 > LDE) e1 = LDE;
  const int ce = e1 - e0;
  for (int t = tid; t < (ce >> 1); t += 256) ((uint32_t*)sb)[t] = 0;
  __syncthreads();
  const int f0 = chunk * FPC;
  const float* xr = xin + (size_t)row * in_f;
#pragma unroll
  for (int j = 0; j < FPC; j += 256) {
    int f = f0 + j + tid;
    if (f < in_f) {
      float sil, b[8];
      spline_expand(xr[f], &sil, b);
      ushort_t* o = &sb[(j + tid) * 9];
      o[0] = f2b(sil);
#pragma unroll
      for (int k = 0; k < 8; ++k) o[1 + k] = f2b(b[k]);
    }
  }
  __syncthreads();
  u32x4* dst = (u32x4*)(A + (size_t)row * LDE + e0);
  const u32x4* src = (const u32x4*)sb;
  const int n16 = ce >> 3;
  for (int t = tid; t < n16; t += 256) dst[t] = src[t];
}

// Both layers' augmented weights in one dispatch.
// grid: (512+384, 3); bx<512 -> layer1 row, else layer2 row (pad rows zeroed).
__global__ __launch_bounds__(256) void prepw_all(
    const float* __restrict__ bw1, const float* __restrict__ sw1, const float* __restrict__ sc1,
    const float* __restrict__ bw2, const float* __restrict__ sw2, const float* __restrict__ sc2,
    ushort_t* __restrict__ W1, ushort_t* __restrict__ W2) {
  __shared__ __align__(16) ushort_t sb[FPC * 9];
  const int bx = blockIdx.x, chunk = blockIdx.y, tid = threadIdx.x;
  const float *bw, *sw, *sc;
  ushort_t* W;
  int o, out_f, in_f, LDE;
  if (bx < 512) { o = bx; out_f = 512; in_f = 2513; LDE = 22624; bw = bw1; sw = sw1; sc = sc1; W = W1; }
  else { o = bx - 512; out_f = 300; in_f = 512; LDE = 4608; bw = bw2; sw = sw2; sc = sc2; W = W2; }
  const int e0 = chunk * (FPC * 9);
  if (e0 >= LDE) return;
  int e1 = e0 + FPC * 9; if (e1 > LDE) e1 = LDE;
  const int ce = e1 - e0;
  for (int t = tid; t < (ce >> 1); t += 256) ((uint32_t*)sb)[t] = 0;
  __syncthreads();
  const int f0 = chunk * FPC;
  if (o < out_f) {
#pragma unroll
    for (int j = 0; j < FPC; j += 256) {
      int f = f0 + j + tid;
      if (f < in_f) {
        size_t base = (size_t)o * in_f + f;
        float s = sc[base];
        float4_t s0 = ((const float4_t*)(sw + base * 8))[0];
        float4_t s1 = ((const float4_t*)(sw + base * 8))[1];
        ushort_t* w = &sb[(j + tid) * 9];
        w[0] = f2b(bw[base]);
        w[1] = f2b(s0.x * s); w[2] = f2b(s0.y * s);
        w[3] = f2b(s0.z * s); w[4] = f2b(s0.w * s);
        w[5] = f2b(s1.x * s); w[6] = f2b(s1.y * s);
        w[7] = f2b(s1.z * s); w[8] = f2b(s1.w * s);
      }
    }
  }
  __syncthreads();
  u32x4* dst = (u32x4*)(W + (size_t)o * LDE + e0);
  const u32x4* src = (const u32x4*)sb;
  const int n16 = ce >> 3;
  for (int t = tid; t < n16; t += 256) dst[t] = src[t];
}

// Sum S layer-1 partials -> relu -> expand into A2 row (512 feats -> 4608 elems).
__global__ __launch_bounds__(256) void reduce_expand_stage(
    const float* __restrict__ P, ushort_t* __restrict__ A2, int M, int S) {
  __shared__ __align__(16) ushort_t sb[4608];
  const int row = blockIdx.x, tid = threadIdx.x;
  const size_t total = (size_t)M * 512;
#pragma unroll
  for (int j = 0; j < 512; j += 256) {
    int f = j + tid;
    float v = 0.0f;
    for (int s = 0; s < S; ++s) v += P[(size_t)s * total + (size_t)row * 512 + f];
    if (v < 0.0f) v = 0.0f;
    float sil, b[8];
    spline_expand(v, &sil, b);
    ushort_t* o = &sb[f * 9];
    o[0] = f2b(sil);
#pragma unroll
    for (int k = 0; k < 8; ++k) o[1 + k] = f2b(b[k]);
  }
  __syncthreads();
  u32x4* dst = (u32x4*)(A2 + (size_t)row * 4608);
  const u32x4* src = (const u32x4*)sb;
  for (int t = tid; t < 576; t += 256) dst[t] = src[t];
}

// Layer-1 GEMM: m97 structure, 128x128 tile, K-split partials P[s,m,n] fp32.
__global__ __launch_bounds__(256) void gemm_kernel(
    const ushort_t* __restrict__ A, const ushort_t* __restrict__ Bw,
    float* __restrict__ P, int M, int N, int K, int kpb) {
  __shared__ __align__(16) ushort_t As[128 * 32];
  __shared__ __align__(16) ushort_t Bs[128 * 32];
  const int tid = threadIdx.x;
  const int m0 = blockIdx.x * 128;
  const int n0 = blockIdx.y * 128;
  const int s = blockIdx.z;
  const int nK = K >> 5;
  int k0 = s * kpb;
  int k1 = k0 + kpb; if (k1 > nK) k1 = nK;
  const int lane = tid & 63;
  const int wv = tid >> 6;
  const int wm = wv & 1, wn = wv >> 1;
  const int l15 = lane & 15, lq = lane >> 4;

  f32x4 acc[4][4];
#pragma unroll
  for (int a = 0; a < 4; ++a)
#pragma unroll
    for (int b = 0; b < 4; ++b) acc[a][b] = {0.0f, 0.0f, 0.0f, 0.0f};

  const int u0 = tid, u1 = tid + 256;
  const int rA0 = u0 >> 2, sA0 = u0 & 3;
  const int rA1 = u1 >> 2, sA1 = u1 & 3;
  const ushort_t* gA0 = A + (size_t)(m0 + rA0) * K + sA0 * 8;
  const ushort_t* gA1 = A + (size_t)(m0 + rA1) * K + sA1 * 8;
  const ushort_t* gB0 = Bw + (size_t)(n0 + rA0) * K + sA0 * 8;
  const ushort_t* gB1 = Bw + (size_t)(n0 + rA1) * K + sA1 * 8;
  ushort_t* lA0 = &As[u0 * 8];
  ushort_t* lA1 = &As[u1 * 8];
  ushort_t* lB0 = &Bs[u0 * 8];
  ushort_t* lB1 = &Bs[u1 * 8];

  for (int kk = k0; kk < k1; ++kk) {
    const int kb = kk << 5;
    __syncthreads();
    __builtin_amdgcn_global_load_lds(GPTR(gA0 + kb), LPTR(lA0), 16, 0, 0);
    __builtin_amdgcn_global_load_lds(GPTR(gA1 + kb), LPTR(lA1), 16, 0, 0);
    __builtin_amdgcn_global_load_lds(GPTR(gB0 + kb), LPTR(lB0), 16, 0, 0);
    __builtin_amdgcn_global_load_lds(GPTR(gB1 + kb), LPTR(lB1), 16, 0, 0);
    __syncthreads();
    bf16x8 aF[4], bF[4];
#pragma unroll
    for (int t = 0; t < 4; ++t) {
      aF[t] = *(const bf16x8*)(&As[(wm * 64 + t * 16 + l15) * 32 + lq * 8]);
      bF[t] = *(const bf16x8*)(&Bs[(wn * 64 + t * 16 + l15) * 32 + lq * 8]);
    }
#pragma unroll
    for (int ti = 0; ti < 4; ++ti)
#pragma unroll
      for (int tj = 0; tj < 4; ++tj)
        acc[ti][tj] = __builtin_amdgcn_mfma_f32_16x16x32_bf16(aF[ti], bF[tj], acc[ti][tj], 0, 0, 0);
  }

  float* Pp = P + (size_t)s * M * N;
#pragma unroll
  for (int ti = 0; ti < 4; ++ti) {
#pragma unroll
    for (int tj = 0; tj < 4; ++tj) {
      int gr = m0 + wm * 64 + ti * 16 + lq * 4;
      int gc = n0 + wn * 64 + tj * 16 + l15;
#pragma unroll
      for (int rr = 0; rr < 4; ++rr) {
        Pp[(size_t)(gr + rr) * N + gc] = acc[ti][tj][rr];
      }
    }
  }
}

// Layer-2 GEMM fused: 64x128 tile, full K (no split), fp32 epilogue direct to out.
// A2 [M,4608] bf16, W2 [384,4608] bf16, out [M,300] fp32. grid (M/64, 3).
__global__ __launch_bounds__(256) void gemm2_fused(
    const ushort_t* __restrict__ A, const ushort_t* __restrict__ Bw,
    float* __restrict__ out, int M) {
  const int K = 4608;
  __shared__ __align__(16) ushort_t As[64 * 32];
  __shared__ __align__(16) ushort_t Bs[128 * 32];
  const int tid = threadIdx.x;
  const int m0 = blockIdx.x * 64;
  const int n0 = blockIdx.y * 128;
  const int lane = tid & 63;
  const int wv = tid >> 6;
  const int wm = wv & 1, wn = wv >> 1;   // wave tile 32(m) x 64(n)
  const int l15 = lane & 15, lq = lane >> 4;

  f32x4 acc[2][4];
#pragma unroll
  for (int a = 0; a < 2; ++a)
#pragma unroll
    for (int b = 0; b < 4; ++b) acc[a][b] = {0.0f, 0.0f, 0.0f, 0.0f};

  const int uA = tid;                    // A: 64 rows x 4 segs = 256 loads
  const int rA = uA >> 2, sA = uA & 3;
  const int u0 = tid, u1 = tid + 256;    // B: 128 rows x 4 segs = 512 loads
  const int rB0 = u0 >> 2, sB0 = u0 & 3;
  const int rB1 = u1 >> 2, sB1 = u1 & 3;
  const ushort_t* gA  = A + (size_t)(m0 + rA) * K + sA * 8;
  const ushort_t* gB0 = Bw + (size_t)(n0 + rB0) * K + sB0 * 8;
  const ushort_t* gB1 = Bw + (size_t)(n0 + rB1) * K + sB1 * 8;
  ushort_t* lA  = &As[uA * 8];
  ushort_t* lB0 = &Bs[u0 * 8];
  ushort_t* lB1 = &Bs[u1 * 8];

  for (int kk = 0; kk < 144; ++kk) {
    const int kb = kk << 5;
    __syncthreads();
    __builtin_amdgcn_global_load_lds(GPTR(gA + kb), LPTR(lA), 16, 0, 0);
    __builtin_amdgcn_global_load_lds(GPTR(gB0 + kb), LPTR(lB0), 16, 0, 0);
    __builtin_amdgcn_global_load_lds(GPTR(gB1 + kb), LPTR(lB1), 16, 0, 0);
    __syncthreads();
    bf16x8 aF[2], bF[4];
#pragma unroll
    for (int t = 0; t < 2; ++t)
      aF[t] = *(const bf16x8*)(&As[(wm * 32 + t * 16 + l15) * 32 + lq * 8]);
#pragma unroll
    for (int t = 0; t < 4; ++t)
      bF[t] = *(const bf16x8*)(&Bs[(wn * 64 + t * 16 + l15) * 32 + lq * 8]);
#pragma unroll
    for (int ti = 0; ti < 2; ++ti)
#pragma unroll
      for (int tj = 0; tj < 4; ++tj)
        acc[ti][tj] = __builtin_amdgcn_mfma_f32_16x16x32_bf16(aF[ti], bF[tj], acc[ti][tj], 0, 0, 0);
  }

#pragma unroll
  for (int ti = 0; ti < 2; ++ti) {
#pragma unroll
    for (int tj = 0; tj < 4; ++tj) {
      int gr = m0 + wm * 32 + ti * 16 + lq * 4;
      int gc = n0 + wn * 64 + tj * 16 + l15;
      if (gc < 300) {
#pragma unroll
        for (int rr = 0; rr < 4; ++rr)
          out[(size_t)(gr + rr) * 300 + gc] = acc[ti][tj][rr];
      }
    }
  }
}

static inline size_t alup(size_t x) { return (x + 255) & ~(size_t)255; }

extern "C" void kernel_launch(void* const* d_in, const int* in_sizes, int n_in,
                              void* d_out, int out_size, void* d_ws, size_t ws_size,
                              hipStream_t stream) {
  const float* fp  = (const float*)d_in[0];   // [8192, 2513] fp32
  const float* bw1 = (const float*)d_in[1];
  const float* sw1 = (const float*)d_in[2];
  const float* sc1 = (const float*)d_in[3];
  const float* bw2 = (const float*)d_in[4];
  const float* sw2 = (const float*)d_in[5];
  const float* sc2 = (const float*)d_in[6];
  float* out = (float*)d_out;                 // [8192, 300] fp32

  const int Btot = 8192, IN1 = 2513, O1 = 512, K1 = 22624;
  const int O2P = 384, K2 = 4608;
  const size_t szW1 = (size_t)O1 * K1 * 2;
  const size_t szW2 = (size_t)O2P * K2 * 2;

  // Adaptive chunking: largest CH that fits ws_size; K-split keeps gemm1 grid ~768 blocks.
  int CH = 256, S1 = 1;
  {
    const int chs[8] = {8192, 4096, 2048, 1024, 512, 256, 256, 256};
    const int s1s[8] = {3, 6, 12, 24, 48, 96, 4, 1};
    for (int t = 0; t < 8; ++t) {
      int ch = chs[t], s1 = s1s[t];
      size_t szP = (size_t)s1 * ch * O1 * 4;
      size_t need = alup(szW1) + alup(szW2) + alup(szP)
                  + alup((size_t)ch * K2 * 2) + alup((size_t)ch * K1 * 2);
      CH = ch; S1 = s1;
      if (need <= ws_size) break;
    }
  }

  char* wp = (char*)d_ws;
  size_t off = 0;
  size_t szP = (size_t)S1 * CH * O1 * 4;
  ushort_t* W1a = (ushort_t*)(wp + off); off += alup(szW1);
  ushort_t* W2a = (ushort_t*)(wp + off); off += alup(szW2);
  float*    P   = (float*)(wp + off);    off += alup(szP);
  ushort_t* A2c = (ushort_t*)(wp + off); off += alup((size_t)CH * K2 * 2);
  ushort_t* A1c = (ushort_t*)(wp + off); off += alup((size_t)CH * K1 * 2);

  const int CH1 = (K1 + FPC * 9 - 1) / (FPC * 9);  // 3 row-chunks for layer-1 width
  prepw_all<<<dim3(O1 + O2P, CH1), 256, 0, stream>>>(bw1, sw1, sc1, bw2, sw2, sc2, W1a, W2a);

  const int nK1 = K1 >> 5;
  const int kpb1 = (nK1 + S1 - 1) / S1;
  const int nch = Btot / CH;
  for (int c = 0; c < nch; ++c) {
    const float* xc = fp + (size_t)c * CH * IN1;
    expand_stage<<<dim3(CH, CH1), 256, 0, stream>>>(xc, A1c, IN1, K1);
    gemm_kernel<<<dim3(CH / 128, O1 / 128, S1), 256, 0, stream>>>(A1c, W1a, P, CH, O1, K1, kpb1);
    reduce_expand_stage<<<CH, 256, 0, stream>>>(P, A2c, CH, S1);
    gemm2_fused<<<dim3(CH / 64, 3), 256, 0, stream>>>(A2c, W2a, out + (size_t)c * CH * 300, CH);
  }
  (void)in_sizes; (void)n_in; (void)out_size;
}

// Round 6
// 699.940 us; speedup vs baseline: 1.1723x; 1.1723x over previous
//
#include <hip/hip_runtime.h>
#include <stdint.h>

typedef unsigned short ushort_t;
typedef __attribute__((ext_vector_type(8))) __bf16 bf16x8;
typedef __attribute__((ext_vector_type(4))) float f32x4;
typedef __attribute__((ext_vector_type(4))) uint32_t u32x4;
typedef __attribute__((ext_vector_type(4))) float float4_t;

#define GPTR(x) ((__attribute__((address_space(1))) void*)(x))
#define LPTR(x) ((__attribute__((address_space(3))) void*)(x))

// Layer-1 K split into 3 feature-thirds: T0/T1 = 838 feats, T2 = 837.
// Each third expands to <=7542 elems, padded to KT=7552 (=236*32).
// W1 row = [T0|T1|T2], stride LDW1 = 3*KT = 22656. A-buffer holds ONE third: [8192, KT].
#define M8   8192
#define KT   7552
#define NKT  236
#define LDW1 22656
#define O1   512
#define K2   4608
#define O2P  384

__device__ __forceinline__ ushort_t f2b(float f) {
  union { float f; uint32_t i; } v; v.f = f;
  uint32_t x = v.i;
  uint32_t r = (x + 0x7FFFu + ((x >> 16) & 1u)) >> 16;  // RNE; finite data only
  return (ushort_t)r;
}

__device__ __forceinline__ void spline_expand(float x, float* sil, float* b /*8*/) {
  *sil = x / (1.0f + __expf(-x));
  float g[12];
#pragma unroll
  for (int j = 0; j < 12; ++j) g[j] = (float)(j - 3) * 0.4f - 1.0f;
  float t[11];
#pragma unroll
  for (int j = 0; j < 11; ++j) t[j] = (x >= g[j] && x < g[j + 1]) ? 1.0f : 0.0f;
#pragma unroll
  for (int k = 1; k <= 3; ++k) {
#pragma unroll
    for (int j = 0; j + k < 11; ++j) {
      float i1 = 1.0f / (g[j + k] - g[j]);        // constant-folded after unroll
      float i2 = 1.0f / (g[j + k + 1] - g[j + 1]);
      t[j] = (x - g[j]) * i1 * t[j] + (g[j + k + 1] - x) * i2 * t[j + 1];
    }
  }
#pragma unroll
  for (int k = 0; k < 8; ++k) b[k] = t[k];
}

// Expand one feature-third of x into A1t [M8, KT]. grid (M8). One block per row.
__global__ __launch_bounds__(256) void expand_third(
    const float* __restrict__ xin, ushort_t* __restrict__ A1t, int f0, int fcnt) {
  __shared__ __align__(16) ushort_t sb[KT];
  const int row = blockIdx.x, tid = threadIdx.x;
  for (int t = tid; t < (KT >> 1); t += 256) ((uint32_t*)sb)[t] = 0;
  __syncthreads();
  const float* xr = xin + (size_t)row * 2513 + f0;
#pragma unroll
  for (int j = 0; j < 1024; j += 256) {
    int fl = j + tid;
    if (fl < fcnt) {
      float sil, b[8];
      spline_expand(xr[fl], &sil, b);
      ushort_t* o = &sb[fl * 9];
      o[0] = f2b(sil);
#pragma unroll
      for (int k = 0; k < 8; ++k) o[1 + k] = f2b(b[k]);
    }
  }
  __syncthreads();
  u32x4* dst = (u32x4*)(A1t + (size_t)row * KT);
  const u32x4* src = (const u32x4*)sb;
  for (int t = tid; t < (KT >> 3); t += 256) dst[t] = src[t];
}

// Both layers' augmented weights. grid (512+384, 3). Layer1 row-thirds (stride LDW1);
// layer2 (bx>=512) uses stride 4608, only c==0.
__global__ __launch_bounds__(256) void prepw_all(
    const float* __restrict__ bw1, const float* __restrict__ sw1, const float* __restrict__ sc1,
    const float* __restrict__ bw2, const float* __restrict__ sw2, const float* __restrict__ sc2,
    ushort_t* __restrict__ W1, ushort_t* __restrict__ W2) {
  __shared__ __align__(16) ushort_t sb[KT];
  const int bx = blockIdx.x, c = blockIdx.y, tid = threadIdx.x;
  const float *bw, *sw, *sc;
  ushort_t* dst;
  int in_f, o, out_f, ce, f0, fcnt;
  if (bx < 512) {
    o = bx; out_f = 512; in_f = 2513;
    ce = KT; f0 = c * 838;
    fcnt = (c == 2) ? 837 : 838;
    dst = W1 + (size_t)o * LDW1 + c * KT;
    bw = bw1; sw = sw1; sc = sc1;
  } else {
    if (c > 0) return;
    o = bx - 512; out_f = 300; in_f = 512;
    ce = K2; f0 = 0; fcnt = 512;
    dst = W2 + (size_t)o * K2;
    bw = bw2; sw = sw2; sc = sc2;
  }
  for (int t = tid; t < (ce >> 1); t += 256) ((uint32_t*)sb)[t] = 0;
  __syncthreads();
  if (o < out_f) {
#pragma unroll
    for (int j = 0; j < 1024; j += 256) {
      int fl = j + tid;
      if (fl < fcnt) {
        size_t base = (size_t)o * in_f + f0 + fl;
        float s = sc[base];
        float4_t s0 = ((const float4_t*)(sw + base * 8))[0];
        float4_t s1 = ((const float4_t*)(sw + base * 8))[1];
        ushort_t* w = &sb[fl * 9];
        w[0] = f2b(bw[base]);
        w[1] = f2b(s0.x * s); w[2] = f2b(s0.y * s);
        w[3] = f2b(s0.z * s); w[4] = f2b(s0.w * s);
        w[5] = f2b(s1.x * s); w[6] = f2b(s1.y * s);
        w[7] = f2b(s1.z * s); w[8] = f2b(s1.w * s);
      }
    }
  }
  __syncthreads();
  u32x4* d4 = (u32x4*)dst;
  const u32x4* s4 = (const u32x4*)sb;
  for (int t = tid; t < (ce >> 3); t += 256) d4[t] = s4[t];
}

// Layer-1 GEMM pass: A [M8, KT], B = W1-third [512 rows, LDW1 stride].
// K-split S=3 -> P[s, M8, O1] fp32; accum=1 -> read-add (passes 1,2).
// 128x128 tile, BK=32, grid (64, 4, 3) = 768 blocks.
__global__ __launch_bounds__(256) void gemm1_kernel(
    const ushort_t* __restrict__ A, const ushort_t* __restrict__ Bw,
    float* __restrict__ P, int accum) {
  __shared__ __align__(16) ushort_t As[128 * 32];
  __shared__ __align__(16) ushort_t Bs[128 * 32];
  const int tid = threadIdx.x;
  const int m0 = blockIdx.x * 128;
  const int n0 = blockIdx.y * 128;
  const int s = blockIdx.z;
  const int k0 = s * 79;
  int k1 = k0 + 79; if (k1 > NKT) k1 = NKT;
  const int lane = tid & 63;
  const int wv = tid >> 6;
  const int wm = wv & 1, wn = wv >> 1;
  const int l15 = lane & 15, lq = lane >> 4;

  f32x4 acc[4][4];
#pragma unroll
  for (int a = 0; a < 4; ++a)
#pragma unroll
    for (int b = 0; b < 4; ++b) acc[a][b] = {0.0f, 0.0f, 0.0f, 0.0f};

  const int u0 = tid, u1 = tid + 256;
  const int rA0 = u0 >> 2, sA0 = u0 & 3;
  const int rA1 = u1 >> 2, sA1 = u1 & 3;
  const ushort_t* gA0 = A + (size_t)(m0 + rA0) * KT + sA0 * 8;
  const ushort_t* gA1 = A + (size_t)(m0 + rA1) * KT + sA1 * 8;
  const ushort_t* gB0 = Bw + (size_t)(n0 + rA0) * LDW1 + sA0 * 8;
  const ushort_t* gB1 = Bw + (size_t)(n0 + rA1) * LDW1 + sA1 * 8;
  ushort_t* lA0 = &As[u0 * 8];
  ushort_t* lA1 = &As[u1 * 8];
  ushort_t* lB0 = &Bs[u0 * 8];
  ushort_t* lB1 = &Bs[u1 * 8];

  for (int kk = k0; kk < k1; ++kk) {
    const int kb = kk << 5;
    __syncthreads();
    __builtin_amdgcn_global_load_lds(GPTR(gA0 + kb), LPTR(lA0), 16, 0, 0);
    __builtin_amdgcn_global_load_lds(GPTR(gA1 + kb), LPTR(lA1), 16, 0, 0);
    __builtin_amdgcn_global_load_lds(GPTR(gB0 + kb), LPTR(lB0), 16, 0, 0);
    __builtin_amdgcn_global_load_lds(GPTR(gB1 + kb), LPTR(lB1), 16, 0, 0);
    __syncthreads();
    bf16x8 aF[4], bF[4];
#pragma unroll
    for (int t = 0; t < 4; ++t) {
      aF[t] = *(const bf16x8*)(&As[(wm * 64 + t * 16 + l15) * 32 + lq * 8]);
      bF[t] = *(const bf16x8*)(&Bs[(wn * 64 + t * 16 + l15) * 32 + lq * 8]);
    }
#pragma unroll
    for (int ti = 0; ti < 4; ++ti)
#pragma unroll
      for (int tj = 0; tj < 4; ++tj)
        acc[ti][tj] = __builtin_amdgcn_mfma_f32_16x16x32_bf16(aF[ti], bF[tj], acc[ti][tj], 0, 0, 0);
  }

  float* Pp = P + (size_t)s * M8 * O1;
#pragma unroll
  for (int ti = 0; ti < 4; ++ti) {
#pragma unroll
    for (int tj = 0; tj < 4; ++tj) {
      int gr = m0 + wm * 64 + ti * 16 + lq * 4;
      int gc = n0 + wn * 64 + tj * 16 + l15;
#pragma unroll
      for (int rr = 0; rr < 4; ++rr) {
        size_t pi = (size_t)(gr + rr) * O1 + gc;
        float v = acc[ti][tj][rr];
        if (accum) v += Pp[pi];
        Pp[pi] = v;
      }
    }
  }
}

// Sum 3 layer-1 partial slices -> relu -> expand into A2 row (512 feats -> 4608).
__global__ __launch_bounds__(256) void reduce_expand_stage(
    const float* __restrict__ P, ushort_t* __restrict__ A2) {
  __shared__ __align__(16) ushort_t sb[K2];
  const int row = blockIdx.x, tid = threadIdx.x;
  const size_t total = (size_t)M8 * O1;
#pragma unroll
  for (int j = 0; j < 512; j += 256) {
    int f = j + tid;
    size_t idx = (size_t)row * O1 + f;
    float v = P[idx] + P[total + idx] + P[2 * total + idx];
    if (v < 0.0f) v = 0.0f;
    float sil, b[8];
    spline_expand(v, &sil, b);
    ushort_t* o = &sb[f * 9];
    o[0] = f2b(sil);
#pragma unroll
    for (int k = 0; k < 8; ++k) o[1 + k] = f2b(b[k]);
  }
  __syncthreads();
  u32x4* dst = (u32x4*)(A2 + (size_t)row * K2);
  const u32x4* src = (const u32x4*)sb;
  for (int t = tid; t < (K2 >> 3); t += 256) dst[t] = src[t];
}

// Layer-2 GEMM: 64x128 tile, K-split S=2 -> P2[s, M8, O2P]. grid (128, 3, 2) = 768.
__global__ __launch_bounds__(256) void gemm2_kernel(
    const ushort_t* __restrict__ A, const ushort_t* __restrict__ Bw,
    float* __restrict__ P2) {
  __shared__ __align__(16) ushort_t As[64 * 32];
  __shared__ __align__(16) ushort_t Bs[128 * 32];
  const int tid = threadIdx.x;
  const int m0 = blockIdx.x * 64;
  const int n0 = blockIdx.y * 128;
  const int s = blockIdx.z;
  const int k0 = s * 72, k1 = k0 + 72;    // 144 = 2*72 exact
  const int lane = tid & 63;
  const int wv = tid >> 6;
  const int wm = wv & 1, wn = wv >> 1;    // wave tile 32(m) x 64(n)
  const int l15 = lane & 15, lq = lane >> 4;

  f32x4 acc[2][4];
#pragma unroll
  for (int a = 0; a < 2; ++a)
#pragma unroll
    for (int b = 0; b < 4; ++b) acc[a][b] = {0.0f, 0.0f, 0.0f, 0.0f};

  const int uA = tid;
  const int rA = uA >> 2, sA = uA & 3;
  const int u0 = tid, u1 = tid + 256;
  const int rB0 = u0 >> 2, sB0 = u0 & 3;
  const int rB1 = u1 >> 2, sB1 = u1 & 3;
  const ushort_t* gA  = A + (size_t)(m0 + rA) * K2 + sA * 8;
  const ushort_t* gB0 = Bw + (size_t)(n0 + rB0) * K2 + sB0 * 8;
  const ushort_t* gB1 = Bw + (size_t)(n0 + rB1) * K2 + sB1 * 8;
  ushort_t* lA  = &As[uA * 8];
  ushort_t* lB0 = &Bs[u0 * 8];
  ushort_t* lB1 = &Bs[u1 * 8];

  for (int kk = k0; kk < k1; ++kk) {
    const int kb = kk << 5;
    __syncthreads();
    __builtin_amdgcn_global_load_lds(GPTR(gA + kb), LPTR(lA), 16, 0, 0);
    __builtin_amdgcn_global_load_lds(GPTR(gB0 + kb), LPTR(lB0), 16, 0, 0);
    __builtin_amdgcn_global_load_lds(GPTR(gB1 + kb), LPTR(lB1), 16, 0, 0);
    __syncthreads();
    bf16x8 aF[2], bF[4];
#pragma unroll
    for (int t = 0; t < 2; ++t)
      aF[t] = *(const bf16x8*)(&As[(wm * 32 + t * 16 + l15) * 32 + lq * 8]);
#pragma unroll
    for (int t = 0; t < 4; ++t)
      bF[t] = *(const bf16x8*)(&Bs[(wn * 64 + t * 16 + l15) * 32 + lq * 8]);
#pragma unroll
    for (int ti = 0; ti < 2; ++ti)
#pragma unroll
      for (int tj = 0; tj < 4; ++tj)
        acc[ti][tj] = __builtin_amdgcn_mfma_f32_16x16x32_bf16(aF[ti], bF[tj], acc[ti][tj], 0, 0, 0);
  }

  float* Pp = P2 + (size_t)s * M8 * O2P;
#pragma unroll
  for (int ti = 0; ti < 2; ++ti) {
#pragma unroll
    for (int tj = 0; tj < 4; ++tj) {
      int gr = m0 + wm * 32 + ti * 16 + lq * 4;
      int gc = n0 + wn * 64 + tj * 16 + l15;
#pragma unroll
      for (int rr = 0; rr < 4; ++rr)
        Pp[(size_t)(gr + rr) * O2P + gc] = acc[ti][tj][rr];
    }
  }
}

// Sum 2 layer-2 partials, drop pad cols, write fp32 out [M8, 300].
__global__ void reduce_out_kernel(const float* __restrict__ P2, float* __restrict__ out) {
  int idx = blockIdx.x * 256 + threadIdx.x;
  const int total = M8 * O2P;
  if (idx >= total) return;
  float v = P2[idx] + P2[(size_t)total + idx];
  int r = idx / O2P, c = idx - r * O2P;
  if (c < 300) out[(size_t)r * 300 + c] = v;
}

static inline size_t alup(size_t x) { return (x + 255) & ~(size_t)255; }

extern "C" void kernel_launch(void* const* d_in, const int* in_sizes, int n_in,
                              void* d_out, int out_size, void* d_ws, size_t ws_size,
                              hipStream_t stream) {
  const float* fp  = (const float*)d_in[0];
  const float* bw1 = (const float*)d_in[1];
  const float* sw1 = (const float*)d_in[2];
  const float* sc1 = (const float*)d_in[3];
  const float* bw2 = (const float*)d_in[4];
  const float* sw2 = (const float*)d_in[5];
  const float* sc2 = (const float*)d_in[6];
  float* out = (float*)d_out;

  char* wp = (char*)d_ws;
  size_t off = 0;
  ushort_t* W1a = (ushort_t*)(wp + off); off += alup((size_t)O1 * LDW1 * 2);   // 23.2 MB
  ushort_t* W2a = (ushort_t*)(wp + off); off += alup((size_t)O2P * K2 * 2);    //  3.5 MB
  float*    P   = (float*)(wp + off);    off += alup((size_t)3 * M8 * O1 * 4); // 50.3 MB
  ushort_t* A2c = (ushort_t*)(wp + off); off += alup((size_t)M8 * K2 * 2);     // 75.5 MB
  ushort_t* A1t = (ushort_t*)(wp + off); off += alup((size_t)M8 * KT * 2);     // 123.7 MB
  // total 276.2 MB — fits the known-safe >=300 MB workspace (R2-R4 CH=4096 tier ran at 300 MB)

  prepw_all<<<dim3(896, 3), 256, 0, stream>>>(bw1, sw1, sc1, bw2, sw2, sc2, W1a, W2a);

  // Layer 1: three feature-third passes, accumulating into 3 shared P slices.
  for (int p = 0; p < 3; ++p) {
    const int f0 = p * 838;
    const int fcnt = (p == 2) ? 837 : 838;
    expand_third<<<M8, 256, 0, stream>>>(fp, A1t, f0, fcnt);
    gemm1_kernel<<<dim3(M8 / 128, O1 / 128, 3), 256, 0, stream>>>(A1t, W1a + p * KT, P, p > 0 ? 1 : 0);
  }

  reduce_expand_stage<<<M8, 256, 0, stream>>>(P, A2c);
  gemm2_kernel<<<dim3(M8 / 64, 3, 2), 256, 0, stream>>>(A2c, W2a, P);
  reduce_out_kernel<<<(M8 * O2P + 255) / 256, 256, 0, stream>>>(P, out);

  (void)in_sizes; (void)n_in; (void)out_size; (void)ws_size;
}